// Round 10
// baseline (76.674 us; speedup 1.0000x reference)
//
#include <hip/hip_runtime.h>
#include <hip/hip_cooperative_groups.h>

namespace cg = cooperative_groups;

// out[b,n] = q^T W_n p ; p=emb[b,R(n)], q=emb[b,C(n)], W_n=kern[:,n,:]
// R10: single cooperative kernel = prep (emb->bf16 swizzled, kern->fragment
// order) + grid.sync + R9 main (BT=64, 32x32x16 MFMA). 256 blocks x 1024 thr,
// 1 block/CU. Eliminates second launch + inter-kernel drain.

#define B_TOT 2048
#define NF    32
#define EMB   64
#define NP    496
#define BT    64

typedef short bf16x8 __attribute__((ext_vector_type(8)));
typedef short bf16x4 __attribute__((ext_vector_type(4)));
typedef float f32x4  __attribute__((ext_vector_type(4)));
typedef float f32x16 __attribute__((ext_vector_type(16)));

static __device__ inline unsigned f2bf(float f) {          // RNE f32->bf16
    unsigned u = __builtin_bit_cast(unsigned, f);
    u += 0x7fffu + ((u >> 16) & 1u);
    return u >> 16;
}
static __device__ inline unsigned pack2(float lo, float hi) {
    return f2bf(lo) | (f2bf(hi) << 16);
}
static __device__ inline float bf2f(short s) {
    return __builtin_bit_cast(float, (unsigned)((unsigned short)s) << 16);
}

#define AS1 __attribute__((address_space(1)))
#define AS3 __attribute__((address_space(3)))

// triu16 pair decode LUT: byte = lr*16 + lc for pig 0..119
__device__ const unsigned char PAIR_T16[120] = {
    0x01,0x02,0x03,0x04,0x05,0x06,0x07,0x08,0x09,0x0A,0x0B,0x0C,0x0D,0x0E,0x0F,
    0x12,0x13,0x14,0x15,0x16,0x17,0x18,0x19,0x1A,0x1B,0x1C,0x1D,0x1E,0x1F,
    0x23,0x24,0x25,0x26,0x27,0x28,0x29,0x2A,0x2B,0x2C,0x2D,0x2E,0x2F,
    0x34,0x35,0x36,0x37,0x38,0x39,0x3A,0x3B,0x3C,0x3D,0x3E,0x3F,
    0x45,0x46,0x47,0x48,0x49,0x4A,0x4B,0x4C,0x4D,0x4E,0x4F,
    0x56,0x57,0x58,0x59,0x5A,0x5B,0x5C,0x5D,0x5E,0x5F,
    0x67,0x68,0x69,0x6A,0x6B,0x6C,0x6D,0x6E,0x6F,
    0x78,0x79,0x7A,0x7B,0x7C,0x7D,0x7E,0x7F,
    0x89,0x8A,0x8B,0x8C,0x8D,0x8E,0x8F,
    0x9A,0x9B,0x9C,0x9D,0x9E,0x9F,
    0xAB,0xAC,0xAD,0xAE,0xAF,
    0xBC,0xBD,0xBE,0xBF,
    0xCD,0xCE,0xCF,
    0xDE,0xDF,
    0xEF
};

__global__ __launch_bounds__(1024) void opnl_fused(
    const float* __restrict__ emb,   // [B][NF][EMB] f32
    const float* __restrict__ kern,  // [EMB(h)][NP][EMB(e)] f32
    short* __restrict__ kb,          // [NP][8][64][8] bf16 32x32-fragment order
    short* __restrict__ ebf,         // [B/16][NF][128 chunks x 8 shorts] swizzled
    float* __restrict__ out)         // [B][NP] f32
{
    __shared__ short elds[64 * 1024];        // 128KB (phase1 reuses first 18KB)

    const int tid = threadIdx.x;

    // ======== phase 1a: emb f32 -> ebf bf16 chunk-swizzled (2 chunks/thread)
#pragma unroll
    for (int jt = 0; jt < 2; ++jt) {
        const int t    = blockIdx.x * 1024 + tid + jt * (256 * 1024);
        const int cidx = t & 127;
        const int f    = (t >> 7) & 31;
        const int bt16 = t >> 12;
        const int bp = cidx >> 3, x = cidx & 7;
        const int ec = x ^ (bp & 7);
        const float* src = emb + (((size_t)(bt16 * 16 + bp) * NF + f) * EMB + ec * 8);
        const f32x4 a = *(const f32x4*)src;
        const f32x4 b = *(const f32x4*)(src + 4);
        uint4 u;
        u.x = pack2(a[0], a[1]); u.y = pack2(a[2], a[3]);
        u.z = pack2(b[0], b[1]); u.w = pack2(b[2], b[3]);
        *(uint4*)(ebf + (size_t)t * 8) = u;
    }

    // ======== phase 1b: kern f32 -> kb bf16 fragment order (2 n per block)
    if (blockIdx.x < 248) {
#pragma unroll
        for (int jn = 0; jn < 2; ++jn) {
            const int n  = blockIdx.x * 2 + jn;
            const int h  = tid >> 4, e4 = tid & 15;
            const f32x4 v = *(const f32x4*)(kern + ((size_t)h * NP + n) * EMB + e4 * 4);
            uint2 u;
            u.x = pack2(v[0], v[1]);
            u.y = pack2(v[2], v[3]);
            *(uint2*)&elds[jn * 4608 + h * 72 + e4 * 4] = u;
        }
        __syncthreads();
        {
            const int jn = tid >> 9, u = tid & 511;
            const int n  = blockIdx.x * 2 + jn;
            const int frag = u >> 6, l = u & 63;
            const int h  = (frag >> 2) * 32 + (l & 31);
            const int e0 = (frag & 3) * 16 + (l >> 5) * 8;
            const bf16x8 t = *(const bf16x8*)&elds[jn * 4608 + h * 72 + e0];
            *(bf16x8*)(kb + (size_t)n * 4096 + u * 8) = t;
        }
    }

    cg::this_grid().sync();

    // ======== phase 2: R9 main body (verified)
    const int type = blockIdx.x >> 5;        // 0..7
    const int bt   = blockIdx.x & 31;        // 0..31
    const int b0   = bt * BT;

    int bLo, bHi, npr;
    switch (type) {
        case 0: case 1: bLo = 0;  bHi = 0;  npr = 60; break;  // fields 0..15
        case 2: case 3: bLo = 16; bHi = 16; npr = 60; break;  // fields 16..31
        case 4:         bLo = 0;  bHi = 8;  npr = 64; break;
        case 5:         bLo = 8;  bHi = 16; npr = 64; break;
        case 6:         bLo = 0;  bHi = 16; npr = 64; break;
        default:        bLo = 8;  bHi = 8;  npr = 64; break;
    }

    const int lane = tid & 63;
    const int wid  = tid >> 6;               // 0..15
    const int bp   = lane & 15;
    const int l5   = lane >> 5;              // 0/1
    const int sub_lo = (lane >> 4) & 1;

    // ---- stage: wave w copies segs 4w..4w+3 (seg = lf*4 + sub16), 2x 1KB each
#pragma unroll
    for (int i = 0; i < 4; ++i) {
        const int s     = wid * 4 + i;
        const int lf    = s >> 2, sub16 = s & 3;
        const int gf    = lf + (lf < 8 ? bLo : bHi);
        const short* src = ebf + ((size_t)((bt * 4 + sub16) * 32 + gf)) * 1024;
        __builtin_amdgcn_global_load_lds((const AS1 void*)(src + lane * 8),
                                         (AS3 void*)&elds[s * 1024], 16, 0, 0);
        __builtin_amdgcn_global_load_lds((const AS1 void*)(src + 512 + lane * 8),
                                         (AS3 void*)&elds[s * 1024 + 512], 16, 0, 0);
    }
    __syncthreads();

    // ---- 4 pairs per wave
    for (int k = 0; k < 4; ++k) {
        int pr = wid + 16 * k;
        if (pr >= npr) pr -= npr;            // wrap: benign duplicate write
        int lr, lc;
        if (type < 4) {
            const int pig = __builtin_amdgcn_readfirstlane((type & 1) * 60 + pr);
            const int byt = PAIR_T16[pig];
            lr = byt >> 4; lc = byt & 15;
        } else {
            lr = pr >> 3; lc = 8 + (pr & 7);
        }
        const int R  = lr + (lr < 8 ? bLo : bHi);
        const int C  = lc + (lc < 8 ? bLo : bHi);
        const int nn = R * (63 - R) / 2 + (C - R - 1);

        // W fragments: 8 coalesced 1KB loads
        bf16x8 wf[2][4];
        const bf16x8* wp = (const bf16x8*)(kb + (size_t)nn * 4096);
#pragma unroll
        for (int mt = 0; mt < 2; ++mt)
#pragma unroll
            for (int ks = 0; ks < 4; ++ks)
                wf[mt][ks] = wp[(mt * 4 + ks) * 64 + lane];

#pragma unroll
        for (int hb = 0; hb < 2; ++hb) {     // b halves of 32
            const int sub16 = hb * 2 + sub_lo;
            const int segp  = (lr * 4 + sub16) * 1024;
            const int segq  = (lc * 4 + sub16) * 1024;

            // B-frags: p[b = b0+hb*32+(lane&31)][e = ks*16 + l5*8 + j]
            bf16x8 pf[4];
#pragma unroll
            for (int ks = 0; ks < 4; ++ks) {
                const int ec = ks * 2 + l5;
                pf[ks] = *(const bf16x8*)&elds[segp + (bp * 8 + (ec ^ (bp & 7))) * 8];
            }

            f32x16 acc[2] = {
                f32x16{0,0,0,0,0,0,0,0,0,0,0,0,0,0,0,0},
                f32x16{0,0,0,0,0,0,0,0,0,0,0,0,0,0,0,0}};
#pragma unroll
            for (int ks = 0; ks < 4; ++ks) {
                acc[0] = __builtin_amdgcn_mfma_f32_32x32x16_bf16(
                    wf[0][ks], pf[ks], acc[0], 0, 0, 0);
                acc[1] = __builtin_amdgcn_mfma_f32_32x32x16_bf16(
                    wf[1][ks], pf[ks], acc[1], 0, 0, 0);
            }

            // epilogue: lane holds U[h = mt*32 + 4*l5 + 8*(reg>>2) + (reg&3), b]
            float val = 0.f;
#pragma unroll
            for (int mt = 0; mt < 2; ++mt) {
#pragma unroll
                for (int rg2 = 0; rg2 < 4; ++rg2) {
                    const bf16x4 qv = *(const bf16x4*)
                        &elds[segq + (bp * 8 + ((mt * 4 + rg2) ^ (bp & 7))) * 8 + l5 * 4];
#pragma unroll
                    for (int i = 0; i < 4; ++i)
                        val = fmaf(acc[mt][rg2 * 4 + i], bf2f(qv[i]), val);
                }
            }
            val += __shfl_xor(val, 32, 64);
            if (lane < 32) out[(size_t)(b0 + hb * 32 + lane) * NP + nn] = val;
        }
    }
}

extern "C" void kernel_launch(void* const* d_in, const int* in_sizes, int n_in,
                              void* d_out, int out_size, void* d_ws, size_t ws_size,
                              hipStream_t stream) {
    const float* emb  = (const float*)d_in[0];   // 2048*32*64
    const float* kern = (const float*)d_in[1];   // 64*496*64
    float*       out  = (float*)d_out;           // 2048*496

    short* kb  = (short*)d_ws;                          // 496*4096 bf16 ~3.9MB
    short* ebf = (short*)((char*)d_ws + (4 << 20));     // 2048*32*64 bf16 = 8MB

    void* args[] = {(void*)&emb, (void*)&kern, (void*)&kb, (void*)&ebf, (void*)&out};
    hipLaunchCooperativeKernel((void*)opnl_fused, dim3(256), dim3(1024),
                               args, 0, stream);
}

// Round 11
// 36.405 us; speedup vs baseline: 2.1061x; 2.1061x over previous
//
#include <hip/hip_runtime.h>

// out[b,n] = q^T W_n p ; p=emb[b,R(n)], q=emb[b,C(n)], W_n=kern[:,n,:]
// R11: drop the ebf prep entirely. Main stages emb f32 -> bf16 directly into
// the swizzled LDS layout (coalesced 128B loads, bank-even ds_write_b64).
// Prep = kern cvt only (496 blocks). Main body (pf/q reads, 32x32x16 MFMA,
// epilogue) bitwise-identical to R9. Grid: type = bid&7 -> one W window/XCD.

#define B_TOT 2048
#define NF    32
#define EMB   64
#define NP    496
#define BT    64

typedef short bf16x8 __attribute__((ext_vector_type(8)));
typedef short bf16x4 __attribute__((ext_vector_type(4)));
typedef float f32x4  __attribute__((ext_vector_type(4)));
typedef float f32x16 __attribute__((ext_vector_type(16)));

static __device__ inline unsigned f2bf(float f) {          // RNE f32->bf16
    unsigned u = __builtin_bit_cast(unsigned, f);
    u += 0x7fffu + ((u >> 16) & 1u);
    return u >> 16;
}
static __device__ inline unsigned pack2(float lo, float hi) {
    return f2bf(lo) | (f2bf(hi) << 16);
}
static __device__ inline float bf2f(short s) {
    return __builtin_bit_cast(float, (unsigned)((unsigned short)s) << 16);
}

// triu16 pair decode LUT: byte = lr*16 + lc for pig 0..119
__device__ const unsigned char PAIR_T16[120] = {
    0x01,0x02,0x03,0x04,0x05,0x06,0x07,0x08,0x09,0x0A,0x0B,0x0C,0x0D,0x0E,0x0F,
    0x12,0x13,0x14,0x15,0x16,0x17,0x18,0x19,0x1A,0x1B,0x1C,0x1D,0x1E,0x1F,
    0x23,0x24,0x25,0x26,0x27,0x28,0x29,0x2A,0x2B,0x2C,0x2D,0x2E,0x2F,
    0x34,0x35,0x36,0x37,0x38,0x39,0x3A,0x3B,0x3C,0x3D,0x3E,0x3F,
    0x45,0x46,0x47,0x48,0x49,0x4A,0x4B,0x4C,0x4D,0x4E,0x4F,
    0x56,0x57,0x58,0x59,0x5A,0x5B,0x5C,0x5D,0x5E,0x5F,
    0x67,0x68,0x69,0x6A,0x6B,0x6C,0x6D,0x6E,0x6F,
    0x78,0x79,0x7A,0x7B,0x7C,0x7D,0x7E,0x7F,
    0x89,0x8A,0x8B,0x8C,0x8D,0x8E,0x8F,
    0x9A,0x9B,0x9C,0x9D,0x9E,0x9F,
    0xAB,0xAC,0xAD,0xAE,0xAF,
    0xBC,0xBD,0xBE,0xBF,
    0xCD,0xCE,0xCF,
    0xDE,0xDF,
    0xEF
};

// ---- prep: kern f32 [h][n][e] -> bf16 32x32-fragment order kb[n][frag][lane][8]
// frag = mt*4+ks ; lane l holds W[h=mt*32+(l&31)][e=ks*16+(l>>5)*8+j]
__global__ __launch_bounds__(256) void prep_kern(const float* __restrict__ kern,
                                                 short* __restrict__ kb) {
    const int n = blockIdx.x;                 // 496 blocks
    __shared__ short w[EMB * 72];
#pragma unroll
    for (int j = 0; j < 4; ++j) {
        const int idx = threadIdx.x + 256 * j;        // (h, e4)
        const int h = idx >> 4, e4 = idx & 15;
        const f32x4 v = *(const f32x4*)(kern + ((size_t)h * NP + n) * EMB + e4 * 4);
        uint2 u;
        u.x = pack2(v[0], v[1]);
        u.y = pack2(v[2], v[3]);
        *(uint2*)&w[h * 72 + e4 * 4] = u;
    }
    __syncthreads();
#pragma unroll
    for (int j = 0; j < 2; ++j) {
        const int u    = threadIdx.x + 256 * j;       // fragment-lane unit
        const int frag = u >> 6, l = u & 63;
        const int h  = (frag >> 2) * 32 + (l & 31);
        const int e0 = (frag & 3) * 16 + (l >> 5) * 8;
        const bf16x8 t = *(const bf16x8*)&w[h * 72 + e0];
        *(bf16x8*)(kb + (size_t)n * 4096 + u * 8) = t;
    }
}

__global__ __launch_bounds__(1024) void opnl_main(
    const float* __restrict__ emb,   // [B][NF][EMB] f32
    const short* __restrict__ kb,    // [NP][8][64][8] bf16 32x32-fragment order
    float* __restrict__ out)         // [B][NP] f32
{
    __shared__ short elds[64 * 1024];        // 64 segs x 2KB = 128KB

    const int type = blockIdx.x & 7;         // one type per XCD (W L2-resident)
    const int bt   = blockIdx.x >> 3;        // 0..31
    const int b0   = bt * BT;

    int bLo, bHi, npr;
    switch (type) {
        case 0: case 1: bLo = 0;  bHi = 0;  npr = 60; break;  // fields 0..15
        case 2: case 3: bLo = 16; bHi = 16; npr = 60; break;  // fields 16..31
        case 4:         bLo = 0;  bHi = 8;  npr = 64; break;
        case 5:         bLo = 8;  bHi = 16; npr = 64; break;
        case 6:         bLo = 0;  bHi = 16; npr = 64; break;
        default:        bLo = 8;  bHi = 8;  npr = 64; break;
    }

    const int tid  = threadIdx.x;
    const int lane = tid & 63;
    const int wid  = tid >> 6;               // 0..15
    const int bp   = lane & 15;
    const int l5   = lane >> 5;              // 0/1
    const int sub_lo = (lane >> 4) & 1;

    // ---- stage emb f32 -> swizzled bf16 LDS directly.
    // run = (b_local, octet): 512 contiguous floats (8 fields x 64e).
    // 8 threads/run; per (s,k): coalesced 128B f32x4 load -> 2 pack2 ->
    // bank-even ds_write_b64 into chunk layout c = bp*8 + (ec ^ (bp&7)).
    {
        const int run = tid >> 3, j = tid & 7;
        const int bl  = run >> 1, o = run & 1;
        const int sub16 = bl >> 4, sbp = bl & 15;
        const int gf0 = o ? (bHi + 8) : bLo;
        const float* src = emb + ((size_t)(b0 + bl) * NF + gf0) * EMB;

        f32x4 v[4][4];
#pragma unroll
        for (int s = 0; s < 4; ++s)
#pragma unroll
            for (int k = 0; k < 4; ++k)
                v[s][k] = *(const f32x4*)(src + s * 128 + k * 32 + j * 4);

#pragma unroll
        for (int s = 0; s < 4; ++s)
#pragma unroll
            for (int k = 0; k < 4; ++k) {
                const int fi   = 2 * s + (k >> 1);         // field within octet
                const int lf   = o ? 8 + fi : fi;
                const int seg  = lf * 4 + sub16;
                const int ec   = (k & 1) * 4 + (j >> 1);   // 8-elem chunk
                const int half = j & 1;
                const int c    = sbp * 8 + (ec ^ (sbp & 7));
                uint2 u;
                u.x = pack2(v[s][k][0], v[s][k][1]);
                u.y = pack2(v[s][k][2], v[s][k][3]);
                *(uint2*)&elds[seg * 1024 + c * 8 + half * 4] = u;
            }
    }
    __syncthreads();

    // ---- 4 pairs per wave (body identical to R9)
    for (int k = 0; k < 4; ++k) {
        int pr = wid + 16 * k;
        if (pr >= npr) pr -= npr;            // wrap: benign duplicate write
        int lr, lc;
        if (type < 4) {
            const int pig = __builtin_amdgcn_readfirstlane((type & 1) * 60 + pr);
            const int byt = PAIR_T16[pig];
            lr = byt >> 4; lc = byt & 15;
        } else {
            lr = pr >> 3; lc = 8 + (pr & 7);
        }
        const int R  = lr + (lr < 8 ? bLo : bHi);
        const int C  = lc + (lc < 8 ? bLo : bHi);
        const int nn = R * (63 - R) / 2 + (C - R - 1);

        // W fragments: 8 coalesced 1KB loads
        bf16x8 wf[2][4];
        const bf16x8* wp = (const bf16x8*)(kb + (size_t)nn * 4096);
#pragma unroll
        for (int mt = 0; mt < 2; ++mt)
#pragma unroll
            for (int ks = 0; ks < 4; ++ks)
                wf[mt][ks] = wp[(mt * 4 + ks) * 64 + lane];

#pragma unroll
        for (int hb = 0; hb < 2; ++hb) {     // b halves of 32
            const int sub16 = hb * 2 + sub_lo;
            const int segp  = (lr * 4 + sub16) * 1024;
            const int segq  = (lc * 4 + sub16) * 1024;

            // B-frags: p[b = b0+hb*32+(lane&31)][e = ks*16 + l5*8 + j]
            bf16x8 pf[4];
#pragma unroll
            for (int ks = 0; ks < 4; ++ks) {
                const int ec = ks * 2 + l5;
                pf[ks] = *(const bf16x8*)&elds[segp + (bp * 8 + (ec ^ (bp & 7))) * 8];
            }

            f32x16 acc[2] = {
                f32x16{0,0,0,0,0,0,0,0,0,0,0,0,0,0,0,0},
                f32x16{0,0,0,0,0,0,0,0,0,0,0,0,0,0,0,0}};
#pragma unroll
            for (int ks = 0; ks < 4; ++ks) {
                acc[0] = __builtin_amdgcn_mfma_f32_32x32x16_bf16(
                    wf[0][ks], pf[ks], acc[0], 0, 0, 0);
                acc[1] = __builtin_amdgcn_mfma_f32_32x32x16_bf16(
                    wf[1][ks], pf[ks], acc[1], 0, 0, 0);
            }

            // epilogue: lane holds U[h = mt*32 + 4*l5 + 8*(reg>>2) + (reg&3), b]
            float val = 0.f;
#pragma unroll
            for (int mt = 0; mt < 2; ++mt) {
#pragma unroll
                for (int rg2 = 0; rg2 < 4; ++rg2) {
                    const bf16x4 qv = *(const bf16x4*)
                        &elds[segq + (bp * 8 + ((mt * 4 + rg2) ^ (bp & 7))) * 8 + l5 * 4];
#pragma unroll
                    for (int i = 0; i < 4; ++i)
                        val = fmaf(acc[mt][rg2 * 4 + i], bf2f(qv[i]), val);
                }
            }
            val += __shfl_xor(val, 32, 64);
            if (lane < 32) out[(size_t)(b0 + hb * 32 + lane) * NP + nn] = val;
        }
    }
}

extern "C" void kernel_launch(void* const* d_in, const int* in_sizes, int n_in,
                              void* d_out, int out_size, void* d_ws, size_t ws_size,
                              hipStream_t stream) {
    const float* emb  = (const float*)d_in[0];   // 2048*32*64
    const float* kern = (const float*)d_in[1];   // 64*496*64
    float*       out  = (float*)d_out;           // 2048*496
    short*       kb   = (short*)d_ws;            // 496*4096 bf16 ~3.9MB

    prep_kern<<<NP, 256, 0, stream>>>(kern, kb);           // 496 blocks
    opnl_main<<<8 * 32, 1024, 0, stream>>>(emb, kb, out);  // 256 blocks, 1/CU
}